// Round 2
// baseline (544.059 us; speedup 1.0000x reference)
//
#include <hip/hip_runtime.h>

#define NN 8192
#define CC 512

typedef __bf16 bhalf;
typedef bhalf bhalf8 __attribute__((ext_vector_type(8)));
typedef bhalf bhalf4 __attribute__((ext_vector_type(4)));
typedef float f32x4 __attribute__((ext_vector_type(4)));

#define AS1 __attribute__((address_space(1)))
#define AS3 __attribute__((address_space(3)))
// async 16B/lane global->LDS; LDS dest = wave-uniform base + lane*16.
// NOTE: the builtin's imm-offset operand applies to BOTH global and LDS
// addresses (LLVM IntrinsicsAMDGPU.td) -- keep it 0, always.
#define GLL16(g, l) \
    __builtin_amdgcn_global_load_lds((const AS1 void*)(g), (AS3 void*)(l), 16, 0, 0)

// Swizzled LDS offset (in shorts) for the 16B chunk `seg` (0..3) of `row` in a
// [rows][32]-short tile. slot = ((row&1)*4 + seg) ^ (pair & 7); all 8
// b128-aligned bank positions covered, exactly 2-way aliasing (free, m136).
// Compatible with GLL16: a 1KB chunk (16 rows, base row % 16 == 0) staged with
// lane -> (row = 2*(lane>>3) + (x>>2), seg = x&3), x = (lane&7)^(lane>>3)
// lands at chunkbase + lane*16 == sw_off of that (row,seg).  (verified algebra;
// rowbase%16==0 => sw_off(rowbase+rin,seg) = rowbase*32 + sw_off(rin,seg))
__device__ __forceinline__ int sw_off(int row, int seg) {
    const int p = row >> 1;
    const int slot = (((row & 1) << 2) | seg) ^ (p & 7);
    return p * 64 + slot * 8;
}

// ---------------------------------------------------------------------------
// out = feat, as a kernel (graph-D2D memcpy uses slow SDMA). FALLBACK PATH ONLY.
// ---------------------------------------------------------------------------
__global__ __launch_bounds__(256) void k_copy(const float4* __restrict__ src,
                                              float4* __restrict__ dst) {
    const int i = blockIdx.x * 256 + threadIdx.x;
    dst[i] = src[i];
}

// ---------------------------------------------------------------------------
// Pass 1: degree sums over A (one full read) + A -> bf16 emit.
// Wave owns 8 rows x 1024 cols (4 float4 col-chunks/row): the 48-shuffle
// row-reduce tree is amortized over 512 B/lane (4x round-3). grid (8,256).
// ---------------------------------------------------------------------------
template <int WRITE_BF16>
__global__ __launch_bounds__(256) void k_degrees(const float* __restrict__ A,
                                                 float* __restrict__ row_deg,
                                                 float* __restrict__ col_deg,
                                                 bhalf* __restrict__ Abf) {
    __shared__ float lcol[1024];
    const int t    = threadIdx.x;
    const int lane = t & 63, wave = t >> 6;
    const int c0 = blockIdx.x * 1024;
    const int r0 = blockIdx.y * 32 + wave * 8;
    lcol[t] = 0.f; lcol[t + 256] = 0.f; lcol[t + 512] = 0.f; lcol[t + 768] = 0.f;
    __syncthreads();

    float colp[16];
#pragma unroll
    for (int j = 0; j < 16; ++j) colp[j] = 0.f;
    float rs[8];
#pragma unroll
    for (int r = 0; r < 8; ++r) rs[r] = 0.f;

#pragma unroll
    for (int ch = 0; ch < 4; ++ch) {
        const int c = c0 + ch * 256 + lane * 4;
#pragma unroll
        for (int r = 0; r < 8; ++r) {
            const float4 v = *(const float4*)(A + (size_t)(r0 + r) * NN + c);
            if (WRITE_BF16) {
                bhalf4 o;
                o[0] = (bhalf)v.x; o[1] = (bhalf)v.y; o[2] = (bhalf)v.z; o[3] = (bhalf)v.w;
                *(bhalf4*)(Abf + (size_t)(r0 + r) * NN + c) = o;
            }
            colp[ch * 4 + 0] += v.x; colp[ch * 4 + 1] += v.y;
            colp[ch * 4 + 2] += v.z; colp[ch * 4 + 3] += v.w;
            rs[r] += (v.x + v.y) + (v.z + v.w);
        }
    }
#pragma unroll
    for (int r = 0; r < 8; ++r) {
#pragma unroll
        for (int off = 32; off; off >>= 1) rs[r] += __shfl_xor(rs[r], off, 64);
    }
    if (lane == 0) {
#pragma unroll
        for (int r = 0; r < 8; ++r) atomicAdd(&row_deg[r0 + r], rs[r]);
    }
#pragma unroll
    for (int ch = 0; ch < 4; ++ch)
#pragma unroll
        for (int j = 0; j < 4; ++j)
            atomicAdd(&lcol[ch * 256 + lane * 4 + j], colp[ch * 4 + j]);
    __syncthreads();
#pragma unroll
    for (int ch = 0; ch < 4; ++ch)
        atomicAdd(&col_deg[c0 + ch * 256 + t], lcol[ch * 256 + t]);
}

// ---------------------------------------------------------------------------
// Pass 2: rsqrt of degrees + zero flag.
// ---------------------------------------------------------------------------
__global__ __launch_bounds__(256) void k_finalize(const float* __restrict__ rd,
                                                  const float* __restrict__ cd,
                                                  float* __restrict__ rsr,
                                                  float* __restrict__ rsc,
                                                  int* __restrict__ flag) {
    const int i = blockIdx.x * 256 + threadIdx.x;
    const float r = rd[i], c = cd[i];
    rsr[i] = (r > 0.f) ? rsqrtf(r) : 0.f;
    rsc[i] = (c > 0.f) ? rsqrtf(c) : 0.f;
    if (r == 0.f || c == 0.f) atomicExch(flag, 1);
}

// ---------------------------------------------------------------------------
// Pass 3: ht[n][k] = relu( sum_c feat[k][c]*W[n][c] + b[n] ) * rsqrt_col[k]
// stored bf16, K-contiguous. 128x128 tile, BK=32, 16x16x32 MFMA. grid=(4,64).
// ---------------------------------------------------------------------------
__global__ __launch_bounds__(256, 2) void k_h(const float* __restrict__ feat,
                                              const float* __restrict__ W,
                                              const float* __restrict__ bias,
                                              const float* __restrict__ rsc,
                                              bhalf* __restrict__ ht) {
    __shared__ __align__(16) bhalf lsA[128 * 32];
    __shared__ __align__(16) bhalf lsB[128 * 32];
    const int n0   = blockIdx.x * 128;
    const int m0   = blockIdx.y * 128;
    const int t    = threadIdx.x;
    const int lane = t & 63, wave = t >> 6;
    const int wm = (wave >> 1) * 64, wn = (wave & 1) * 64;
    const int quad = lane >> 4, rsel = lane & 15;
    f32x4 acc[4][4];
#pragma unroll
    for (int a = 0; a < 4; ++a)
#pragma unroll
        for (int bq = 0; bq < 4; ++bq)
#pragma unroll
            for (int e = 0; e < 4; ++e) acc[a][bq][e] = 0.f;

    for (int k0 = 0; k0 < CC; k0 += 32) {
#pragma unroll
        for (int i = 0; i < 4; ++i) {
            const int ch = i * 256 + t;
            const int r = ch >> 3, s8 = ch & 7;
            const int lo = sw_off(r, s8 >> 1) + (s8 & 1) * 4;
            const float4 v = *(const float4*)(feat + (size_t)(m0 + r) * CC + k0 + s8 * 4);
            bhalf4 o;
            o[0] = (bhalf)v.x; o[1] = (bhalf)v.y; o[2] = (bhalf)v.z; o[3] = (bhalf)v.w;
            *(bhalf4*)(lsA + lo) = o;
            const float4 w = *(const float4*)(W + (size_t)(n0 + r) * CC + k0 + s8 * 4);
            bhalf4 ow;
            ow[0] = (bhalf)w.x; ow[1] = (bhalf)w.y; ow[2] = (bhalf)w.z; ow[3] = (bhalf)w.w;
            *(bhalf4*)(lsB + lo) = ow;
        }
        __syncthreads();
        bhalf8 af[4], bf[4];
#pragma unroll
        for (int x = 0; x < 4; ++x) {
            af[x] = *(const bhalf8*)(lsA + sw_off(wm + x * 16 + rsel, quad));
            bf[x] = *(const bhalf8*)(lsB + sw_off(wn + x * 16 + rsel, quad));
        }
#pragma unroll
        for (int mt = 0; mt < 4; ++mt)
#pragma unroll
            for (int nt = 0; nt < 4; ++nt)
                acc[mt][nt] = __builtin_amdgcn_mfma_f32_16x16x32_bf16(af[mt], bf[nt],
                                                                      acc[mt][nt], 0, 0, 0);
        __syncthreads();
    }
#pragma unroll
    for (int mt = 0; mt < 4; ++mt) {
        const int kbase = m0 + wm + mt * 16 + quad * 4;
        const float s0 = rsc[kbase + 0], s1 = rsc[kbase + 1];
        const float s2 = rsc[kbase + 2], s3 = rsc[kbase + 3];
#pragma unroll
        for (int nt = 0; nt < 4; ++nt) {
            const int n = n0 + wn + nt * 16 + rsel;
            const float bn = bias[n];
            bhalf4 o;
            o[0] = (bhalf)(fmaxf(acc[mt][nt][0] + bn, 0.f) * s0);
            o[1] = (bhalf)(fmaxf(acc[mt][nt][1] + bn, 0.f) * s1);
            o[2] = (bhalf)(fmaxf(acc[mt][nt][2] + bn, 0.f) * s2);
            o[3] = (bhalf)(fmaxf(acc[mt][nt][3] + bn, 0.f) * s3);
            *(bhalf4*)(ht + (size_t)n * NN + kbase) = o;
        }
    }
}

// ---------------------------------------------------------------------------
// Pass 4 (fast path): part[z] = A16_tile @ ht_tile  (plain coalesced stores,
// NO atomics; identity/rsr/flag handled by k_reduce).
// Block = 512 thr / 8 waves (2m x 4n), tile 128(m) x 256(n), BK=64 as two
// BK=32 sub-tiles, K-split 4.  Chunk->wave map: (wgrp=wave&3, khalf=wave>>2);
// wave stages 2 A-chunks (rows wgrp*32+{0,16}) + 4 B-chunks (rows
// wgrp*64+{0,16,32,48}) of its k-half.  All 6 global bases differ by >=256 KB
// (no imm-offset folding possible); every GLL16 uses imm offset 0 and an
// explicit wave-uniform LDS base.  32 MFMA per barrier pair (drains halved).
// LDS 48 KB -> 2 blocks/CU. grid (2,64,4)=512 blocks.
// ---------------------------------------------------------------------------
__global__ __launch_bounds__(512, 4) void k_gemm2_bf(const bhalf* __restrict__ A16,
                                                     const bhalf* __restrict__ ht,
                                                     float* __restrict__ part) {
    __shared__ __align__(16) bhalf lsA[2][128 * 32];  // 16 KB (two BK=32 sub-tiles)
    __shared__ __align__(16) bhalf lsB[2][256 * 32];  // 32 KB
    const int n0   = blockIdx.x * 256;
    const int m0   = blockIdx.y * 128;
    const int K0   = blockIdx.z * (NN / 4);
    const int t    = threadIdx.x;
    const int lane = t & 63, wave = t >> 6;  // 8 waves
    const int wm = (wave >> 2) * 64, wn = (wave & 3) * 64;
    const int quad = lane >> 4, rsel = lane & 15;

    // staging decomposition
    const int wgrp = wave & 3, khalf = wave >> 2;
    // lane-permuted global source for swizzle-compatible GLL16 staging
    const int x   = (lane & 7) ^ ((lane >> 3) & 7);
    const int rin = 2 * (lane >> 3) + (x >> 2);  // row-in-chunk 0..15
    const int seg = x & 3;
    const int kcol = K0 + khalf * 32 + seg * 8;

    const bhalf* gA0 = A16 + (size_t)(m0 + wgrp * 32 +  0 + rin) * NN + kcol;
    const bhalf* gA1 = A16 + (size_t)(m0 + wgrp * 32 + 16 + rin) * NN + kcol;
    const bhalf* gB0 = ht  + (size_t)(n0 + wgrp * 64 +  0 + rin) * NN + kcol;
    const bhalf* gB1 = ht  + (size_t)(n0 + wgrp * 64 + 16 + rin) * NN + kcol;
    const bhalf* gB2 = ht  + (size_t)(n0 + wgrp * 64 + 32 + rin) * NN + kcol;
    const bhalf* gB3 = ht  + (size_t)(n0 + wgrp * 64 + 48 + rin) * NN + kcol;
    bhalf* const lA0 = &lsA[khalf][0] + (wgrp * 32 +  0) * 32;
    bhalf* const lA1 = &lsA[khalf][0] + (wgrp * 32 + 16) * 32;
    bhalf* const lB0 = &lsB[khalf][0] + (wgrp * 64 +  0) * 32;
    bhalf* const lB1 = &lsB[khalf][0] + (wgrp * 64 + 16) * 32;
    bhalf* const lB2 = &lsB[khalf][0] + (wgrp * 64 + 32) * 32;
    bhalf* const lB3 = &lsB[khalf][0] + (wgrp * 64 + 48) * 32;

    f32x4 acc[4][4];
#pragma unroll
    for (int a = 0; a < 4; ++a)
#pragma unroll
        for (int bq = 0; bq < 4; ++bq)
#pragma unroll
            for (int e = 0; e < 4; ++e) acc[a][bq][e] = 0.f;

    for (int it = 0; it < (NN / 4) / 64; ++it) {
        GLL16(gA0, lA0);
        GLL16(gA1, lA1);
        GLL16(gB0, lB0);
        GLL16(gB1, lB1);
        GLL16(gB2, lB2);
        GLL16(gB3, lB3);
        gA0 += 64; gA1 += 64; gB0 += 64; gB1 += 64; gB2 += 64; gB3 += 64;
        __syncthreads();  // drains vmcnt (compiler-inserted) -> staging visible
#pragma unroll
        for (int kk = 0; kk < 2; ++kk) {
            const bhalf* const bA = &lsA[kk][0];
            const bhalf* const bB = &lsB[kk][0];
            bhalf8 af[4], bf[4];
#pragma unroll
            for (int i = 0; i < 4; ++i) {
                af[i] = *(const bhalf8*)(bA + sw_off(wm + i * 16 + rsel, quad));
                bf[i] = *(const bhalf8*)(bB + sw_off(wn + i * 16 + rsel, quad));
            }
#pragma unroll
            for (int mt = 0; mt < 4; ++mt)
#pragma unroll
                for (int nt = 0; nt < 4; ++nt)
                    acc[mt][nt] = __builtin_amdgcn_mfma_f32_16x16x32_bf16(
                        af[mt], bf[nt], acc[mt][nt], 0, 0, 0);
        }
        __syncthreads();
    }
    // plain coalesced partial stores (no atomics, no flag dependence)
    float* const p = part + (size_t)blockIdx.z * NN * CC;
#pragma unroll
    for (int mt = 0; mt < 4; ++mt) {
        const int ibase = m0 + wm + mt * 16 + quad * 4;
#pragma unroll
        for (int rg = 0; rg < 4; ++rg) {
            const int i = ibase + rg;
#pragma unroll
            for (int nt = 0; nt < 4; ++nt) {
                const int j = n0 + wn + nt * 16 + rsel;
                p[(size_t)i * CC + j] = acc[mt][nt][rg];
            }
        }
    }
}

// ---------------------------------------------------------------------------
// Pass 5 (fast path): out = flag ? feat : feat + rsr[i] * sum_z part[z].
// 96 MB streaming pass; replaces k_copy + 16.7M f32 atomics. grid 4096x256.
// ---------------------------------------------------------------------------
__global__ __launch_bounds__(256) void k_reduce(const float4* __restrict__ feat,
                                                const float4* __restrict__ part,
                                                const float* __restrict__ rsr,
                                                const int* __restrict__ flag,
                                                float4* __restrict__ out) {
    const int idx = blockIdx.x * 256 + threadIdx.x;  // over NN*CC/4 float4s
    float4 f = feat[idx];
    if (!*flag) {
        const size_t str = (size_t)NN * CC / 4;
        const float4 a = part[idx];
        const float4 b = part[idx + str];
        const float4 c = part[idx + 2 * str];
        const float4 d = part[idx + 3 * str];
        const float r = rsr[idx >> 7];  // CC/4 = 128 float4 per row
        f.x += r * ((a.x + b.x) + (c.x + d.x));
        f.y += r * ((a.y + b.y) + (c.y + d.y));
        f.z += r * ((a.z + b.z) + (c.z + d.z));
        f.w += r * ((a.w + b.w) + (c.w + d.w));
    }
    out[idx] = f;
}

// ---------------------------------------------------------------------------
// Pass 4 (fallback, no bf16 ws): round-3 structure with fp32->bf16 convert.
// Atomic epilogue onto out pre-initialized to feat by k_copy.
// ---------------------------------------------------------------------------
__global__ __launch_bounds__(256, 3) void k_gemm2_f32(const float* __restrict__ A32,
                                                      const bhalf* __restrict__ ht,
                                                      const float* __restrict__ rsr,
                                                      const int* __restrict__ flag,
                                                      float* __restrict__ out) {
    __shared__ __align__(16) bhalf lsA[128 * 32];
    __shared__ __align__(16) bhalf lsB[128 * 32];
    const int n0   = blockIdx.x * 128;
    const int m0   = blockIdx.y * 128;
    const int K0   = blockIdx.z * (NN / 4);
    const int t    = threadIdx.x;
    const int lane = t & 63, wave = t >> 6;
    const int wm = (wave >> 1) * 64, wn = (wave & 1) * 64;
    const int quad = lane >> 4, rsel = lane & 15;
    f32x4 acc[4][4];
#pragma unroll
    for (int a = 0; a < 4; ++a)
#pragma unroll
        for (int bq = 0; bq < 4; ++bq)
#pragma unroll
            for (int e = 0; e < 4; ++e) acc[a][bq][e] = 0.f;

    for (int k0 = K0; k0 < K0 + NN / 4; k0 += 32) {
#pragma unroll
        for (int i = 0; i < 4; ++i) {
            const int ch = i * 256 + t;
            const int r = ch >> 3, s8 = ch & 7;
            const float4 v = *(const float4*)(A32 + (size_t)(m0 + r) * NN + k0 + s8 * 4);
            bhalf4 o;
            o[0] = (bhalf)v.x; o[1] = (bhalf)v.y; o[2] = (bhalf)v.z; o[3] = (bhalf)v.w;
            *(bhalf4*)(lsA + sw_off(r, s8 >> 1) + (s8 & 1) * 4) = o;
        }
#pragma unroll
        for (int i = 0; i < 2; ++i) {
            const int ch = i * 256 + t;
            const int r = ch >> 2, seg = ch & 3;
            const bhalf8 v = *(const bhalf8*)(ht + (size_t)(n0 + r) * NN + k0 + seg * 8);
            *(bhalf8*)(lsB + sw_off(r, seg)) = v;
        }
        __syncthreads();
        bhalf8 af[4], bf[4];
#pragma unroll
        for (int i = 0; i < 4; ++i) {
            af[i] = *(const bhalf8*)(lsA + sw_off(wm + i * 16 + rsel, quad));
            bf[i] = *(const bhalf8*)(lsB + sw_off(wn + i * 16 + rsel, quad));
        }
#pragma unroll
        for (int mt = 0; mt < 4; ++mt)
#pragma unroll
            for (int nt = 0; nt < 4; ++nt)
                acc[mt][nt] = __builtin_amdgcn_mfma_f32_16x16x32_bf16(af[mt], bf[nt],
                                                                      acc[mt][nt], 0, 0, 0);
        __syncthreads();
    }
    const int fl = *flag;
    if (fl) return;
#pragma unroll
    for (int mt = 0; mt < 4; ++mt) {
        const int ibase = m0 + wm + mt * 16 + quad * 4;
#pragma unroll
        for (int rg = 0; rg < 4; ++rg) {
            const int i   = ibase + rg;
            const float s = rsr[i];
#pragma unroll
            for (int nt = 0; nt < 4; ++nt) {
                const int j = n0 + wn + nt * 16 + rsel;
                atomicAdd(&out[(size_t)i * CC + j], s * acc[mt][nt][rg]);
            }
        }
    }
}

// ---------------------------------------------------------------------------
// Workspace layout:
//   0         row_deg  f32[8192]
//   32768     col_deg  f32[8192]
//   65536     rsqrt_row f32[8192]
//   98304     rsqrt_col f32[8192]
//   131072    flag int
//   262144    ht bf16[512*8192]         (8 MB)
//   16777216  A_bf16 bf16[8192*8192]    (128 MB)
//   150994944 partials f32[4][8192*512] (64 MB)
// ---------------------------------------------------------------------------
extern "C" void kernel_launch(void* const* d_in, const int* in_sizes, int n_in,
                              void* d_out, int out_size, void* d_ws, size_t ws_size,
                              hipStream_t stream) {
    const float* feat = (const float*)d_in[0];
    const float* adj  = (const float*)d_in[1];
    const float* W    = (const float*)d_in[2];
    const float* bias = (const float*)d_in[3];
    float* out = (float*)d_out;

    char* ws       = (char*)d_ws;
    float* row_deg = (float*)(ws);
    float* col_deg = (float*)(ws + 32768);
    float* rsr     = (float*)(ws + 65536);
    float* rsc     = (float*)(ws + 98304);
    int* flag      = (int*)(ws + 131072);
    bhalf* ht      = (bhalf*)(ws + 262144);
    bhalf* Abf     = (bhalf*)(ws + 16777216);
    float* part    = (float*)(ws + 150994944);

    const bool use_bf16 =
        ws_size >= (size_t)150994944 + (size_t)4 * NN * CC * sizeof(float);

    hipMemsetAsync(d_ws, 0, 131072 + 64, stream);

    if (use_bf16) {
        k_degrees<1><<<dim3(8, 256), 256, 0, stream>>>(adj, row_deg, col_deg, Abf);
        k_finalize<<<32, 256, 0, stream>>>(row_deg, col_deg, rsr, rsc, flag);
        k_h<<<dim3(4, 64), 256, 0, stream>>>(feat, W, bias, rsc, ht);
        k_gemm2_bf<<<dim3(2, 64, 4), 512, 0, stream>>>(Abf, ht, part);
        k_reduce<<<NN * CC / 4 / 256, 256, 0, stream>>>((const float4*)feat,
                                                        (const float4*)part, rsr, flag,
                                                        (float4*)out);
    } else {
        k_copy<<<NN * CC / 4 / 256, 256, 0, stream>>>((const float4*)feat, (float4*)out);
        k_degrees<0><<<dim3(8, 256), 256, 0, stream>>>(adj, row_deg, col_deg, nullptr);
        k_finalize<<<32, 256, 0, stream>>>(row_deg, col_deg, rsr, rsc, flag);
        k_h<<<dim3(4, 64), 256, 0, stream>>>(feat, W, bias, rsc, ht);
        k_gemm2_f32<<<dim3(4, 64, 4), 256, 0, stream>>>(adj, ht, rsr, flag, out);
    }
}

// Round 3
// 524.965 us; speedup vs baseline: 1.0364x; 1.0364x over previous
//
#include <hip/hip_runtime.h>

#define NN 8192
#define CC 512

typedef __bf16 bhalf;
typedef bhalf bhalf8 __attribute__((ext_vector_type(8)));
typedef bhalf bhalf4 __attribute__((ext_vector_type(4)));
typedef float f32x4 __attribute__((ext_vector_type(4)));

#define AS1 __attribute__((address_space(1)))
#define AS3 __attribute__((address_space(3)))
// async 16B/lane global->LDS; LDS dest = wave-uniform base + lane*16.
// NOTE: the builtin's imm-offset operand applies to BOTH global and LDS
// addresses (LLVM IntrinsicsAMDGPU.td) -- keep it 0, always.
#define GLL16(g, l) \
    __builtin_amdgcn_global_load_lds((const AS1 void*)(g), (AS3 void*)(l), 16, 0, 0)

// Swizzled LDS offset (in shorts) for the 16B chunk `seg` (0..3) of `row` in a
// [rows][32]-short tile. slot = ((row&1)*4 + seg) ^ (pair & 7); all 8
// b128-aligned bank positions covered, exactly 2-way aliasing (free, m136).
// Compatible with GLL16: a 1KB chunk (16 rows, base row % 16 == 0) staged with
// lane -> (row = 2*(lane>>3) + (x>>2), seg = x&3), x = (lane&7)^(lane>>3)
// lands at chunkbase + lane*16 == sw_off of that (row,seg).  (verified algebra;
// rowbase%16==0 => sw_off(rowbase+rin,seg) = rowbase*32 + sw_off(rin,seg))
__device__ __forceinline__ int sw_off(int row, int seg) {
    const int p = row >> 1;
    const int slot = (((row & 1) << 2) | seg) ^ (p & 7);
    return p * 64 + slot * 8;
}

// ---------------------------------------------------------------------------
// out = feat, as a kernel (graph-D2D memcpy uses slow SDMA). FALLBACK PATH ONLY.
// ---------------------------------------------------------------------------
__global__ __launch_bounds__(256) void k_copy(const float4* __restrict__ src,
                                              float4* __restrict__ dst) {
    const int i = blockIdx.x * 256 + threadIdx.x;
    dst[i] = src[i];
}

// ---------------------------------------------------------------------------
// Pass 1: degree sums over A (one full read) + A -> bf16 emit.
// Wave owns 8 rows x 1024 cols (4 float4 col-chunks/row): the 48-shuffle
// row-reduce tree is amortized over 512 B/lane (4x round-3). grid (8,256).
// ---------------------------------------------------------------------------
template <int WRITE_BF16>
__global__ __launch_bounds__(256) void k_degrees(const float* __restrict__ A,
                                                 float* __restrict__ row_deg,
                                                 float* __restrict__ col_deg,
                                                 bhalf* __restrict__ Abf) {
    __shared__ float lcol[1024];
    const int t    = threadIdx.x;
    const int lane = t & 63, wave = t >> 6;
    const int c0 = blockIdx.x * 1024;
    const int r0 = blockIdx.y * 32 + wave * 8;
    lcol[t] = 0.f; lcol[t + 256] = 0.f; lcol[t + 512] = 0.f; lcol[t + 768] = 0.f;
    __syncthreads();

    float colp[16];
#pragma unroll
    for (int j = 0; j < 16; ++j) colp[j] = 0.f;
    float rs[8];
#pragma unroll
    for (int r = 0; r < 8; ++r) rs[r] = 0.f;

#pragma unroll
    for (int ch = 0; ch < 4; ++ch) {
        const int c = c0 + ch * 256 + lane * 4;
#pragma unroll
        for (int r = 0; r < 8; ++r) {
            const float4 v = *(const float4*)(A + (size_t)(r0 + r) * NN + c);
            if (WRITE_BF16) {
                bhalf4 o;
                o[0] = (bhalf)v.x; o[1] = (bhalf)v.y; o[2] = (bhalf)v.z; o[3] = (bhalf)v.w;
                *(bhalf4*)(Abf + (size_t)(r0 + r) * NN + c) = o;
            }
            colp[ch * 4 + 0] += v.x; colp[ch * 4 + 1] += v.y;
            colp[ch * 4 + 2] += v.z; colp[ch * 4 + 3] += v.w;
            rs[r] += (v.x + v.y) + (v.z + v.w);
        }
    }
#pragma unroll
    for (int r = 0; r < 8; ++r) {
#pragma unroll
        for (int off = 32; off; off >>= 1) rs[r] += __shfl_xor(rs[r], off, 64);
    }
    if (lane == 0) {
#pragma unroll
        for (int r = 0; r < 8; ++r) atomicAdd(&row_deg[r0 + r], rs[r]);
    }
#pragma unroll
    for (int ch = 0; ch < 4; ++ch)
#pragma unroll
        for (int j = 0; j < 4; ++j)
            atomicAdd(&lcol[ch * 256 + lane * 4 + j], colp[ch * 4 + j]);
    __syncthreads();
#pragma unroll
    for (int ch = 0; ch < 4; ++ch)
        atomicAdd(&col_deg[c0 + ch * 256 + t], lcol[ch * 256 + t]);
}

// ---------------------------------------------------------------------------
// Pass 2: rsqrt of degrees + zero flag.
// ---------------------------------------------------------------------------
__global__ __launch_bounds__(256) void k_finalize(const float* __restrict__ rd,
                                                  const float* __restrict__ cd,
                                                  float* __restrict__ rsr,
                                                  float* __restrict__ rsc,
                                                  int* __restrict__ flag) {
    const int i = blockIdx.x * 256 + threadIdx.x;
    const float r = rd[i], c = cd[i];
    rsr[i] = (r > 0.f) ? rsqrtf(r) : 0.f;
    rsc[i] = (c > 0.f) ? rsqrtf(c) : 0.f;
    if (r == 0.f || c == 0.f) atomicExch(flag, 1);
}

// ---------------------------------------------------------------------------
// Pass 3: ht[n][k] = relu( sum_c feat[k][c]*W[n][c] + b[n] ) * rsqrt_col[k]
// stored bf16, K-contiguous. 128x128 tile, BK=32, 16x16x32 MFMA. grid=(4,64).
// ---------------------------------------------------------------------------
__global__ __launch_bounds__(256, 2) void k_h(const float* __restrict__ feat,
                                              const float* __restrict__ W,
                                              const float* __restrict__ bias,
                                              const float* __restrict__ rsc,
                                              bhalf* __restrict__ ht) {
    __shared__ __align__(16) bhalf lsA[128 * 32];
    __shared__ __align__(16) bhalf lsB[128 * 32];
    const int n0   = blockIdx.x * 128;
    const int m0   = blockIdx.y * 128;
    const int t    = threadIdx.x;
    const int lane = t & 63, wave = t >> 6;
    const int wm = (wave >> 1) * 64, wn = (wave & 1) * 64;
    const int quad = lane >> 4, rsel = lane & 15;
    f32x4 acc[4][4];
#pragma unroll
    for (int a = 0; a < 4; ++a)
#pragma unroll
        for (int bq = 0; bq < 4; ++bq)
#pragma unroll
            for (int e = 0; e < 4; ++e) acc[a][bq][e] = 0.f;

    for (int k0 = 0; k0 < CC; k0 += 32) {
#pragma unroll
        for (int i = 0; i < 4; ++i) {
            const int ch = i * 256 + t;
            const int r = ch >> 3, s8 = ch & 7;
            const int lo = sw_off(r, s8 >> 1) + (s8 & 1) * 4;
            const float4 v = *(const float4*)(feat + (size_t)(m0 + r) * CC + k0 + s8 * 4);
            bhalf4 o;
            o[0] = (bhalf)v.x; o[1] = (bhalf)v.y; o[2] = (bhalf)v.z; o[3] = (bhalf)v.w;
            *(bhalf4*)(lsA + lo) = o;
            const float4 w = *(const float4*)(W + (size_t)(n0 + r) * CC + k0 + s8 * 4);
            bhalf4 ow;
            ow[0] = (bhalf)w.x; ow[1] = (bhalf)w.y; ow[2] = (bhalf)w.z; ow[3] = (bhalf)w.w;
            *(bhalf4*)(lsB + lo) = ow;
        }
        __syncthreads();
        bhalf8 af[4], bf[4];
#pragma unroll
        for (int x = 0; x < 4; ++x) {
            af[x] = *(const bhalf8*)(lsA + sw_off(wm + x * 16 + rsel, quad));
            bf[x] = *(const bhalf8*)(lsB + sw_off(wn + x * 16 + rsel, quad));
        }
#pragma unroll
        for (int mt = 0; mt < 4; ++mt)
#pragma unroll
            for (int nt = 0; nt < 4; ++nt)
                acc[mt][nt] = __builtin_amdgcn_mfma_f32_16x16x32_bf16(af[mt], bf[nt],
                                                                      acc[mt][nt], 0, 0, 0);
        __syncthreads();
    }
#pragma unroll
    for (int mt = 0; mt < 4; ++mt) {
        const int kbase = m0 + wm + mt * 16 + quad * 4;
        const float s0 = rsc[kbase + 0], s1 = rsc[kbase + 1];
        const float s2 = rsc[kbase + 2], s3 = rsc[kbase + 3];
#pragma unroll
        for (int nt = 0; nt < 4; ++nt) {
            const int n = n0 + wn + nt * 16 + rsel;
            const float bn = bias[n];
            bhalf4 o;
            o[0] = (bhalf)(fmaxf(acc[mt][nt][0] + bn, 0.f) * s0);
            o[1] = (bhalf)(fmaxf(acc[mt][nt][1] + bn, 0.f) * s1);
            o[2] = (bhalf)(fmaxf(acc[mt][nt][2] + bn, 0.f) * s2);
            o[3] = (bhalf)(fmaxf(acc[mt][nt][3] + bn, 0.f) * s3);
            *(bhalf4*)(ht + (size_t)n * NN + kbase) = o;
        }
    }
}

// ---------------------------------------------------------------------------
// Pass 4 (fast path): part[z] = A16_tile @ ht_tile  (plain coalesced stores).
// Block = 512 thr / 8 waves (2m x 4n), tile 128(m) x 256(n), BK=32, K-split 4.
// T3/T4 2-phase pipeline: two LDS sub-buffers ping-pong; step t+1's 3 GLL16
// are issued BEFORE computing step t; s_waitcnt vmcnt(3) + raw s_barrier
// (never a vmcnt(0) drain in the main loop) keeps next-step loads in flight
// across the MFMA phase.  Hazards: stage(t+1) overwrites buf(t-1), whose reads
// finished before the trailing barrier of step t-1; stage(t)'s visibility is
// vmcnt(3)+barrier before compute(t).  T1: bijective XCD swizzle (512=8x64)
// groups each XCD on 64 consecutive tiles (fixed z) -> per-XCD ht working set
// 512x2048x2B = 2MB, L2-resident; x-pair A-slice L2-hit on 2nd read.
// LDS 48 KB -> 2 blocks/CU (grid 512 = exactly 2/CU).
// ---------------------------------------------------------------------------
__global__ __launch_bounds__(512, 4) void k_gemm2_bf(const bhalf* __restrict__ A16,
                                                     const bhalf* __restrict__ ht,
                                                     float* __restrict__ part) {
    __shared__ __align__(16) bhalf lsA[2][128 * 32];  // 16 KB (ping-pong BK=32)
    __shared__ __align__(16) bhalf lsB[2][256 * 32];  // 32 KB
    // T1: bijective XCD swizzle (nwg=512, 8 XCDs, 512%8==0)
    const int flat = blockIdx.x + 2 * (blockIdx.y + 64 * blockIdx.z);
    const int tl   = (flat & 7) * 64 + (flat >> 3);
    const int n0   = (tl & 1) * 256;
    const int m0   = ((tl >> 1) & 63) * 128;
    const int zz   = tl >> 7;
    const int K0   = zz * (NN / 4);
    const int t    = threadIdx.x;
    const int lane = t & 63, wave = t >> 6;  // 8 waves
    const int wm = (wave >> 2) * 64, wn = (wave & 3) * 64;
    const int quad = lane >> 4, rsel = lane & 15;

    // lane-permuted global source for swizzle-compatible GLL16 staging
    const int x   = (lane & 7) ^ ((lane >> 3) & 7);
    const int rin = 2 * (lane >> 3) + (x >> 2);  // row-in-chunk 0..15
    const int seg = x & 3;
    const bhalf* g0 = A16 + (size_t)(m0 + wave * 16 + rin) * NN + K0 + seg * 8;
    const bhalf* g1 = ht + (size_t)(n0 + wave * 16 + rin) * NN + K0 + seg * 8;
    const bhalf* g2 = ht + (size_t)(n0 + 128 + wave * 16 + rin) * NN + K0 + seg * 8;
    bhalf* const l0 = &lsA[0][0] + wave * 512;        // +4096 shorts for buf 1
    bhalf* const l1 = &lsB[0][0] + wave * 512;        // +8192 shorts for buf 1
    bhalf* const l2 = &lsB[0][0] + (wave + 8) * 512;

    f32x4 acc[4][4];
#pragma unroll
    for (int a = 0; a < 4; ++a)
#pragma unroll
        for (int bq = 0; bq < 4; ++bq)
#pragma unroll
            for (int e = 0; e < 4; ++e) acc[a][bq][e] = 0.f;

    // prologue: stage step 0 into buf 0 (3 loads in flight)
    GLL16(g0, l0);
    GLL16(g1, l1);
    GLL16(g2, l2);
    g0 += 32; g1 += 32; g2 += 32;

#pragma unroll 2
    for (int it = 0; it < 64; ++it) {
        if (it < 63) {
            const int nb = (it + 1) & 1;
            GLL16(g0, l0 + nb * 4096);
            GLL16(g1, l1 + nb * 8192);
            GLL16(g2, l2 + nb * 8192);
            g0 += 32; g1 += 32; g2 += 32;
            // wait for step-it's 3 loads (oldest of <=6); keep next 3 in flight
            asm volatile("s_waitcnt vmcnt(3)" ::: "memory");
        } else {
            asm volatile("s_waitcnt vmcnt(0)" ::: "memory");
        }
        __builtin_amdgcn_sched_barrier(0);
        __builtin_amdgcn_s_barrier();  // staging of buf(it&1) visible to all
        const int cb = it & 1;
        const bhalf* const bA = &lsA[0][0] + cb * 4096;
        const bhalf* const bB = &lsB[0][0] + cb * 8192;
        bhalf8 af[4], bf[4];
#pragma unroll
        for (int i = 0; i < 4; ++i) {
            af[i] = *(const bhalf8*)(bA + sw_off(wm + i * 16 + rsel, quad));
            bf[i] = *(const bhalf8*)(bB + sw_off(wn + i * 16 + rsel, quad));
        }
        __builtin_amdgcn_s_setprio(1);
#pragma unroll
        for (int mt = 0; mt < 4; ++mt)
#pragma unroll
            for (int nt = 0; nt < 4; ++nt)
                acc[mt][nt] = __builtin_amdgcn_mfma_f32_16x16x32_bf16(
                    af[mt], bf[nt], acc[mt][nt], 0, 0, 0);
        __builtin_amdgcn_s_setprio(0);
        __builtin_amdgcn_sched_barrier(0);
        __builtin_amdgcn_s_barrier();  // all reads of buf(it&1) done before reuse
    }
    // plain coalesced partial stores (no atomics, no flag dependence)
    float* const p = part + (size_t)zz * NN * CC;
#pragma unroll
    for (int mt = 0; mt < 4; ++mt) {
        const int ibase = m0 + wm + mt * 16 + quad * 4;
#pragma unroll
        for (int rg = 0; rg < 4; ++rg) {
            const int i = ibase + rg;
#pragma unroll
            for (int nt = 0; nt < 4; ++nt) {
                const int j = n0 + wn + nt * 16 + rsel;
                p[(size_t)i * CC + j] = acc[mt][nt][rg];
            }
        }
    }
}

// ---------------------------------------------------------------------------
// Pass 5 (fast path): out = flag ? feat : feat + rsr[i] * sum_z part[z].
// 96 MB streaming pass; replaces k_copy + 16.7M f32 atomics. grid 4096x256.
// ---------------------------------------------------------------------------
__global__ __launch_bounds__(256) void k_reduce(const float4* __restrict__ feat,
                                                const float4* __restrict__ part,
                                                const float* __restrict__ rsr,
                                                const int* __restrict__ flag,
                                                float4* __restrict__ out) {
    const int idx = blockIdx.x * 256 + threadIdx.x;  // over NN*CC/4 float4s
    float4 f = feat[idx];
    if (!*flag) {
        const size_t str = (size_t)NN * CC / 4;
        const float4 a = part[idx];
        const float4 b = part[idx + str];
        const float4 c = part[idx + 2 * str];
        const float4 d = part[idx + 3 * str];
        const float r = rsr[idx >> 7];  // CC/4 = 128 float4 per row
        f.x += r * ((a.x + b.x) + (c.x + d.x));
        f.y += r * ((a.y + b.y) + (c.y + d.y));
        f.z += r * ((a.z + b.z) + (c.z + d.z));
        f.w += r * ((a.w + b.w) + (c.w + d.w));
    }
    out[idx] = f;
}

// ---------------------------------------------------------------------------
// Pass 4 (fallback, no bf16 ws): round-3 structure with fp32->bf16 convert.
// Atomic epilogue onto out pre-initialized to feat by k_copy.
// ---------------------------------------------------------------------------
__global__ __launch_bounds__(256, 3) void k_gemm2_f32(const float* __restrict__ A32,
                                                      const bhalf* __restrict__ ht,
                                                      const float* __restrict__ rsr,
                                                      const int* __restrict__ flag,
                                                      float* __restrict__ out) {
    __shared__ __align__(16) bhalf lsA[128 * 32];
    __shared__ __align__(16) bhalf lsB[128 * 32];
    const int n0   = blockIdx.x * 128;
    const int m0   = blockIdx.y * 128;
    const int K0   = blockIdx.z * (NN / 4);
    const int t    = threadIdx.x;
    const int lane = t & 63, wave = t >> 6;
    const int wm = (wave >> 1) * 64, wn = (wave & 1) * 64;
    const int quad = lane >> 4, rsel = lane & 15;
    f32x4 acc[4][4];
#pragma unroll
    for (int a = 0; a < 4; ++a)
#pragma unroll
        for (int bq = 0; bq < 4; ++bq)
#pragma unroll
            for (int e = 0; e < 4; ++e) acc[a][bq][e] = 0.f;

    for (int k0 = K0; k0 < K0 + NN / 4; k0 += 32) {
#pragma unroll
        for (int i = 0; i < 4; ++i) {
            const int ch = i * 256 + t;
            const int r = ch >> 3, s8 = ch & 7;
            const float4 v = *(const float4*)(A32 + (size_t)(m0 + r) * NN + k0 + s8 * 4);
            bhalf4 o;
            o[0] = (bhalf)v.x; o[1] = (bhalf)v.y; o[2] = (bhalf)v.z; o[3] = (bhalf)v.w;
            *(bhalf4*)(lsA + sw_off(r, s8 >> 1) + (s8 & 1) * 4) = o;
        }
#pragma unroll
        for (int i = 0; i < 2; ++i) {
            const int ch = i * 256 + t;
            const int r = ch >> 2, seg = ch & 3;
            const bhalf8 v = *(const bhalf8*)(ht + (size_t)(n0 + r) * NN + k0 + seg * 8);
            *(bhalf8*)(lsB + sw_off(r, seg)) = v;
        }
        __syncthreads();
        bhalf8 af[4], bf[4];
#pragma unroll
        for (int i = 0; i < 4; ++i) {
            af[i] = *(const bhalf8*)(lsA + sw_off(wm + i * 16 + rsel, quad));
            bf[i] = *(const bhalf8*)(lsB + sw_off(wn + i * 16 + rsel, quad));
        }
#pragma unroll
        for (int mt = 0; mt < 4; ++mt)
#pragma unroll
            for (int nt = 0; nt < 4; ++nt)
                acc[mt][nt] = __builtin_amdgcn_mfma_f32_16x16x32_bf16(af[mt], bf[nt],
                                                                      acc[mt][nt], 0, 0, 0);
        __syncthreads();
    }
    const int fl = *flag;
    if (fl) return;
#pragma unroll
    for (int mt = 0; mt < 4; ++mt) {
        const int ibase = m0 + wm + mt * 16 + quad * 4;
#pragma unroll
        for (int rg = 0; rg < 4; ++rg) {
            const int i   = ibase + rg;
            const float s = rsr[i];
#pragma unroll
            for (int nt = 0; nt < 4; ++nt) {
                const int j = n0 + wn + nt * 16 + rsel;
                atomicAdd(&out[(size_t)i * CC + j], s * acc[mt][nt][rg]);
            }
        }
    }
}

// ---------------------------------------------------------------------------
// Workspace layout:
//   0         row_deg  f32[8192]
//   32768     col_deg  f32[8192]
//   65536     rsqrt_row f32[8192]
//   98304     rsqrt_col f32[8192]
//   131072    flag int
//   262144    ht bf16[512*8192]         (8 MB)
//   16777216  A_bf16 bf16[8192*8192]    (128 MB)
//   150994944 partials f32[4][8192*512] (64 MB)
// ---------------------------------------------------------------------------
extern "C" void kernel_launch(void* const* d_in, const int* in_sizes, int n_in,
                              void* d_out, int out_size, void* d_ws, size_t ws_size,
                              hipStream_t stream) {
    const float* feat = (const float*)d_in[0];
    const float* adj  = (const float*)d_in[1];
    const float* W    = (const float*)d_in[2];
    const float* bias = (const float*)d_in[3];
    float* out = (float*)d_out;

    char* ws       = (char*)d_ws;
    float* row_deg = (float*)(ws);
    float* col_deg = (float*)(ws + 32768);
    float* rsr     = (float*)(ws + 65536);
    float* rsc     = (float*)(ws + 98304);
    int* flag      = (int*)(ws + 131072);
    bhalf* ht      = (bhalf*)(ws + 262144);
    bhalf* Abf     = (bhalf*)(ws + 16777216);
    float* part    = (float*)(ws + 150994944);

    const bool use_bf16 =
        ws_size >= (size_t)150994944 + (size_t)4 * NN * CC * sizeof(float);

    hipMemsetAsync(d_ws, 0, 131072 + 64, stream);

    if (use_bf16) {
        k_degrees<1><<<dim3(8, 256), 256, 0, stream>>>(adj, row_deg, col_deg, Abf);
        k_finalize<<<32, 256, 0, stream>>>(row_deg, col_deg, rsr, rsc, flag);
        k_h<<<dim3(4, 64), 256, 0, stream>>>(feat, W, bias, rsc, ht);
        k_gemm2_bf<<<dim3(2, 64, 4), 512, 0, stream>>>(Abf, ht, part);
        k_reduce<<<NN * CC / 4 / 256, 256, 0, stream>>>((const float4*)feat,
                                                        (const float4*)part, rsr, flag,
                                                        (float4*)out);
    } else {
        k_copy<<<NN * CC / 4 / 256, 256, 0, stream>>>((const float4*)feat, (float4*)out);
        k_degrees<0><<<dim3(8, 256), 256, 0, stream>>>(adj, row_deg, col_deg, nullptr);
        k_finalize<<<32, 256, 0, stream>>>(row_deg, col_deg, rsr, rsc, flag);
        k_h<<<dim3(4, 64), 256, 0, stream>>>(feat, W, bias, rsc, ht);
        k_gemm2_f32<<<dim3(4, 64, 4), 256, 0, stream>>>(adj, ht, rsr, flag, out);
    }
}

// Round 4
// 518.211 us; speedup vs baseline: 1.0499x; 1.0130x over previous
//
#include <hip/hip_runtime.h>

#define NN 8192
#define CC 512

typedef __bf16 bhalf;
typedef bhalf bhalf8 __attribute__((ext_vector_type(8)));
typedef bhalf bhalf4 __attribute__((ext_vector_type(4)));
typedef float f32x4 __attribute__((ext_vector_type(4)));

#define AS1 __attribute__((address_space(1)))
#define AS3 __attribute__((address_space(3)))
// async 16B/lane global->LDS; LDS dest = wave-uniform base + lane*16.
// NOTE: the builtin's imm-offset operand applies to BOTH global and LDS
// addresses (LLVM IntrinsicsAMDGPU.td) -- keep it 0, always.
#define GLL16(g, l) \
    __builtin_amdgcn_global_load_lds((const AS1 void*)(g), (AS3 void*)(l), 16, 0, 0)

// Swizzled LDS offset (in shorts) for the 16B chunk `seg` (0..3) of `row` in a
// [rows][32]-short tile. slot = ((row&1)*4 + seg) ^ (pair & 7); all 8
// b128-aligned bank positions covered, exactly 2-way aliasing (free, m136).
// Compatible with GLL16: a 1KB chunk (16 rows, base row % 16 == 0) staged with
// lane -> (row = 2*(lane>>3) + (x>>2), seg = x&3), x = (lane&7)^(lane>>3)
// lands at chunkbase + lane*16 == sw_off of that (row,seg).  (verified algebra;
// rowbase%16==0 => sw_off(rowbase+rin,seg) = rowbase*32 + sw_off(rin,seg))
__device__ __forceinline__ int sw_off(int row, int seg) {
    const int p = row >> 1;
    const int slot = (((row & 1) << 2) | seg) ^ (p & 7);
    return p * 64 + slot * 8;
}

// ---------------------------------------------------------------------------
// out = feat, as a kernel (graph-D2D memcpy uses slow SDMA). FALLBACK PATH ONLY.
// ---------------------------------------------------------------------------
__global__ __launch_bounds__(256) void k_copy(const float4* __restrict__ src,
                                              float4* __restrict__ dst) {
    const int i = blockIdx.x * 256 + threadIdx.x;
    dst[i] = src[i];
}

// ---------------------------------------------------------------------------
// Pass 1: degree sums over A (one full read) + A -> bf16 emit.
// Wave owns 8 rows x 1024 cols (4 float4 col-chunks/row): the 48-shuffle
// row-reduce tree is amortized over 512 B/lane (4x round-3). grid (8,256).
// ---------------------------------------------------------------------------
template <int WRITE_BF16>
__global__ __launch_bounds__(256) void k_degrees(const float* __restrict__ A,
                                                 float* __restrict__ row_deg,
                                                 float* __restrict__ col_deg,
                                                 bhalf* __restrict__ Abf) {
    __shared__ float lcol[1024];
    const int t    = threadIdx.x;
    const int lane = t & 63, wave = t >> 6;
    const int c0 = blockIdx.x * 1024;
    const int r0 = blockIdx.y * 32 + wave * 8;
    lcol[t] = 0.f; lcol[t + 256] = 0.f; lcol[t + 512] = 0.f; lcol[t + 768] = 0.f;
    __syncthreads();

    float colp[16];
#pragma unroll
    for (int j = 0; j < 16; ++j) colp[j] = 0.f;
    float rs[8];
#pragma unroll
    for (int r = 0; r < 8; ++r) rs[r] = 0.f;

#pragma unroll
    for (int ch = 0; ch < 4; ++ch) {
        const int c = c0 + ch * 256 + lane * 4;
#pragma unroll
        for (int r = 0; r < 8; ++r) {
            const float4 v = *(const float4*)(A + (size_t)(r0 + r) * NN + c);
            if (WRITE_BF16) {
                bhalf4 o;
                o[0] = (bhalf)v.x; o[1] = (bhalf)v.y; o[2] = (bhalf)v.z; o[3] = (bhalf)v.w;
                *(bhalf4*)(Abf + (size_t)(r0 + r) * NN + c) = o;
            }
            colp[ch * 4 + 0] += v.x; colp[ch * 4 + 1] += v.y;
            colp[ch * 4 + 2] += v.z; colp[ch * 4 + 3] += v.w;
            rs[r] += (v.x + v.y) + (v.z + v.w);
        }
    }
#pragma unroll
    for (int r = 0; r < 8; ++r) {
#pragma unroll
        for (int off = 32; off; off >>= 1) rs[r] += __shfl_xor(rs[r], off, 64);
    }
    if (lane == 0) {
#pragma unroll
        for (int r = 0; r < 8; ++r) atomicAdd(&row_deg[r0 + r], rs[r]);
    }
#pragma unroll
    for (int ch = 0; ch < 4; ++ch)
#pragma unroll
        for (int j = 0; j < 4; ++j)
            atomicAdd(&lcol[ch * 256 + lane * 4 + j], colp[ch * 4 + j]);
    __syncthreads();
#pragma unroll
    for (int ch = 0; ch < 4; ++ch)
        atomicAdd(&col_deg[c0 + ch * 256 + t], lcol[ch * 256 + t]);
}

// ---------------------------------------------------------------------------
// Pass 2: rsqrt of degrees + zero flag.
// ---------------------------------------------------------------------------
__global__ __launch_bounds__(256) void k_finalize(const float* __restrict__ rd,
                                                  const float* __restrict__ cd,
                                                  float* __restrict__ rsr,
                                                  float* __restrict__ rsc,
                                                  int* __restrict__ flag) {
    const int i = blockIdx.x * 256 + threadIdx.x;
    const float r = rd[i], c = cd[i];
    rsr[i] = (r > 0.f) ? rsqrtf(r) : 0.f;
    rsc[i] = (c > 0.f) ? rsqrtf(c) : 0.f;
    if (r == 0.f || c == 0.f) atomicExch(flag, 1);
}

// ---------------------------------------------------------------------------
// Pass 3: ht[n][k] = relu( sum_c feat[k][c]*W[n][c] + b[n] ) * rsqrt_col[k]
// stored bf16, K-contiguous. 128x128 tile, BK=32, 16x16x32 MFMA. grid=(4,64).
// ---------------------------------------------------------------------------
__global__ __launch_bounds__(256, 2) void k_h(const float* __restrict__ feat,
                                              const float* __restrict__ W,
                                              const float* __restrict__ bias,
                                              const float* __restrict__ rsc,
                                              bhalf* __restrict__ ht) {
    __shared__ __align__(16) bhalf lsA[128 * 32];
    __shared__ __align__(16) bhalf lsB[128 * 32];
    const int n0   = blockIdx.x * 128;
    const int m0   = blockIdx.y * 128;
    const int t    = threadIdx.x;
    const int lane = t & 63, wave = t >> 6;
    const int wm = (wave >> 1) * 64, wn = (wave & 1) * 64;
    const int quad = lane >> 4, rsel = lane & 15;
    f32x4 acc[4][4];
#pragma unroll
    for (int a = 0; a < 4; ++a)
#pragma unroll
        for (int bq = 0; bq < 4; ++bq)
#pragma unroll
            for (int e = 0; e < 4; ++e) acc[a][bq][e] = 0.f;

    for (int k0 = 0; k0 < CC; k0 += 32) {
#pragma unroll
        for (int i = 0; i < 4; ++i) {
            const int ch = i * 256 + t;
            const int r = ch >> 3, s8 = ch & 7;
            const int lo = sw_off(r, s8 >> 1) + (s8 & 1) * 4;
            const float4 v = *(const float4*)(feat + (size_t)(m0 + r) * CC + k0 + s8 * 4);
            bhalf4 o;
            o[0] = (bhalf)v.x; o[1] = (bhalf)v.y; o[2] = (bhalf)v.z; o[3] = (bhalf)v.w;
            *(bhalf4*)(lsA + lo) = o;
            const float4 w = *(const float4*)(W + (size_t)(n0 + r) * CC + k0 + s8 * 4);
            bhalf4 ow;
            ow[0] = (bhalf)w.x; ow[1] = (bhalf)w.y; ow[2] = (bhalf)w.z; ow[3] = (bhalf)w.w;
            *(bhalf4*)(lsB + lo) = ow;
        }
        __syncthreads();
        bhalf8 af[4], bf[4];
#pragma unroll
        for (int x = 0; x < 4; ++x) {
            af[x] = *(const bhalf8*)(lsA + sw_off(wm + x * 16 + rsel, quad));
            bf[x] = *(const bhalf8*)(lsB + sw_off(wn + x * 16 + rsel, quad));
        }
#pragma unroll
        for (int mt = 0; mt < 4; ++mt)
#pragma unroll
            for (int nt = 0; nt < 4; ++nt)
                acc[mt][nt] = __builtin_amdgcn_mfma_f32_16x16x32_bf16(af[mt], bf[nt],
                                                                      acc[mt][nt], 0, 0, 0);
        __syncthreads();
    }
#pragma unroll
    for (int mt = 0; mt < 4; ++mt) {
        const int kbase = m0 + wm + mt * 16 + quad * 4;
        const float s0 = rsc[kbase + 0], s1 = rsc[kbase + 1];
        const float s2 = rsc[kbase + 2], s3 = rsc[kbase + 3];
#pragma unroll
        for (int nt = 0; nt < 4; ++nt) {
            const int n = n0 + wn + nt * 16 + rsel;
            const float bn = bias[n];
            bhalf4 o;
            o[0] = (bhalf)(fmaxf(acc[mt][nt][0] + bn, 0.f) * s0);
            o[1] = (bhalf)(fmaxf(acc[mt][nt][1] + bn, 0.f) * s1);
            o[2] = (bhalf)(fmaxf(acc[mt][nt][2] + bn, 0.f) * s2);
            o[3] = (bhalf)(fmaxf(acc[mt][nt][3] + bn, 0.f) * s3);
            *(bhalf4*)(ht + (size_t)n * NN + kbase) = o;
        }
    }
}

// ---------------------------------------------------------------------------
// Pass 4 (fast path): part[z] = A16_tile @ ht_tile  (bf16 coalesced stores).
// Block = 512 thr / 8 waves (2m x 4n), tile 128(m) x 256(n), BK=32, K-split 4.
// T3/T4 3-stage pipeline: three LDS buffer sets rotate; stage t+2's 3 GLL16
// issued BEFORE computing step t (prefetch distance 2 iters ~2600cy >> 900cy
// HBM latency); steady-state s_waitcnt vmcnt(6) (9 issued, oldest 3 retired;
// vmcnt retires in order, m135).  Hazard: stage(t+2) overwrites buf(t-1),
// whose ds_reads completed before iter t-1's trailing barrier.  Epilogue
// drains: it==62 -> vmcnt(3), it==63 -> vmcnt(0).
// T1: bijective XCD swizzle (512=8x64): fixed n-half + z-grouped runs per XCD
// -> per-XCD ht working set 1 MB, L2-resident.  T5 setprio around MFMA.
// LDS 72 KB -> 2 blocks/CU (144 KB).  grid (2,64,4) = 512 blocks = 2/CU.
// ---------------------------------------------------------------------------
__global__ __launch_bounds__(512, 4) void k_gemm2_bf(const bhalf* __restrict__ A16,
                                                     const bhalf* __restrict__ ht,
                                                     bhalf* __restrict__ part) {
    __shared__ __align__(16) bhalf lsA[3][128 * 32];  // 24 KB (3-stage rotate)
    __shared__ __align__(16) bhalf lsB[3][256 * 32];  // 48 KB
    // T1: bijective XCD swizzle (nwg=512, 8 XCDs, 512%8==0)
    const int flat = blockIdx.x + 2 * (blockIdx.y + 64 * blockIdx.z);
    const int tl   = (flat & 7) * 64 + (flat >> 3);
    const int n0   = (tl & 1) * 256;
    const int m0   = ((tl >> 1) & 63) * 128;
    const int zz   = tl >> 7;
    const int K0   = zz * (NN / 4);
    const int t    = threadIdx.x;
    const int lane = t & 63, wave = t >> 6;  // 8 waves
    const int wm = (wave >> 2) * 64, wn = (wave & 3) * 64;
    const int quad = lane >> 4, rsel = lane & 15;

    // lane-permuted global source for swizzle-compatible GLL16 staging
    const int x   = (lane & 7) ^ ((lane >> 3) & 7);
    const int rin = 2 * (lane >> 3) + (x >> 2);  // row-in-chunk 0..15
    const int seg = x & 3;
    const bhalf* g0 = A16 + (size_t)(m0 + wave * 16 + rin) * NN + K0 + seg * 8;
    const bhalf* g1 = ht + (size_t)(n0 + wave * 16 + rin) * NN + K0 + seg * 8;
    const bhalf* g2 = ht + (size_t)(n0 + 128 + wave * 16 + rin) * NN + K0 + seg * 8;
    bhalf* const l0 = &lsA[0][0] + wave * 512;        // +4096 shorts per A-stage
    bhalf* const l1 = &lsB[0][0] + wave * 512;        // +8192 shorts per B-stage
    bhalf* const l2 = &lsB[0][0] + (wave + 8) * 512;

    f32x4 acc[4][4];
#pragma unroll
    for (int a = 0; a < 4; ++a)
#pragma unroll
        for (int bq = 0; bq < 4; ++bq)
#pragma unroll
            for (int e = 0; e < 4; ++e) acc[a][bq][e] = 0.f;

    // prologue: stage iters 0,1 into buffers 0,1 (6 loads in flight)
    GLL16(g0, l0);
    GLL16(g1, l1);
    GLL16(g2, l2);
    g0 += 32; g1 += 32; g2 += 32;
    GLL16(g0, l0 + 4096);
    GLL16(g1, l1 + 8192);
    GLL16(g2, l2 + 8192);
    g0 += 32; g1 += 32; g2 += 32;

    int cur = 0, stg = 2;  // buffer of iter `it`; buffer to stage (it+2)
    for (int it = 0; it < 64; ++it) {
        if (it < 62) {
            GLL16(g0, l0 + stg * 4096);
            GLL16(g1, l1 + stg * 8192);
            GLL16(g2, l2 + stg * 8192);
            g0 += 32; g1 += 32; g2 += 32;
            // oldest 3 (iter it's stage) retired; 6 stay in flight
            asm volatile("s_waitcnt vmcnt(6)" ::: "memory");
        } else if (it == 62) {
            asm volatile("s_waitcnt vmcnt(3)" ::: "memory");
        } else {
            asm volatile("s_waitcnt vmcnt(0)" ::: "memory");
        }
        __builtin_amdgcn_sched_barrier(0);
        __builtin_amdgcn_s_barrier();  // staging of buf(cur) visible to all
        const bhalf* const bA = &lsA[0][0] + cur * 4096;
        const bhalf* const bB = &lsB[0][0] + cur * 8192;
        bhalf8 af[4], bf[4];
#pragma unroll
        for (int i = 0; i < 4; ++i) {
            af[i] = *(const bhalf8*)(bA + sw_off(wm + i * 16 + rsel, quad));
            bf[i] = *(const bhalf8*)(bB + sw_off(wn + i * 16 + rsel, quad));
        }
        __builtin_amdgcn_s_setprio(1);
#pragma unroll
        for (int mt = 0; mt < 4; ++mt)
#pragma unroll
            for (int nt = 0; nt < 4; ++nt)
                acc[mt][nt] = __builtin_amdgcn_mfma_f32_16x16x32_bf16(
                    af[mt], bf[nt], acc[mt][nt], 0, 0, 0);
        __builtin_amdgcn_s_setprio(0);
        __builtin_amdgcn_sched_barrier(0);
        __builtin_amdgcn_s_barrier();  // all reads of buf(cur) done before reuse
        cur = (cur == 2) ? 0 : cur + 1;
        stg = (stg == 2) ? 0 : stg + 1;
    }
    // bf16 partial stores (no atomics, no flag dependence); quantization adds
    // ~2e-4 abs to out (threshold 0.104) -- halves part traffic.
    bhalf* const p = part + (size_t)zz * NN * CC;
#pragma unroll
    for (int mt = 0; mt < 4; ++mt) {
        const int ibase = m0 + wm + mt * 16 + quad * 4;
#pragma unroll
        for (int rg = 0; rg < 4; ++rg) {
            const int i = ibase + rg;
#pragma unroll
            for (int nt = 0; nt < 4; ++nt) {
                const int j = n0 + wn + nt * 16 + rsel;
                p[(size_t)i * CC + j] = (bhalf)acc[mt][nt][rg];
            }
        }
    }
}

// ---------------------------------------------------------------------------
// Pass 5 (fast path): out = flag ? feat : feat + rsr[i] * sum_z part[z].
// 64 MB streaming pass (bf16 partials). grid 4096x256.
// ---------------------------------------------------------------------------
__global__ __launch_bounds__(256) void k_reduce(const float4* __restrict__ feat,
                                                const bhalf* __restrict__ part,
                                                const float* __restrict__ rsr,
                                                const int* __restrict__ flag,
                                                float4* __restrict__ out) {
    const int idx = blockIdx.x * 256 + threadIdx.x;  // over NN*CC/4 float4s
    float4 f = feat[idx];
    if (!*flag) {
        const size_t str = (size_t)NN * CC;
        const bhalf4 a = *(const bhalf4*)(part + idx * 4);
        const bhalf4 b = *(const bhalf4*)(part + str + idx * 4);
        const bhalf4 c = *(const bhalf4*)(part + 2 * str + idx * 4);
        const bhalf4 d = *(const bhalf4*)(part + 3 * str + idx * 4);
        const float r = rsr[idx >> 7];  // CC/4 = 128 float4 per row
        f.x += r * (((float)a[0] + (float)b[0]) + ((float)c[0] + (float)d[0]));
        f.y += r * (((float)a[1] + (float)b[1]) + ((float)c[1] + (float)d[1]));
        f.z += r * (((float)a[2] + (float)b[2]) + ((float)c[2] + (float)d[2]));
        f.w += r * (((float)a[3] + (float)b[3]) + ((float)c[3] + (float)d[3]));
    }
    out[idx] = f;
}

// ---------------------------------------------------------------------------
// Pass 4 (fallback, no bf16 ws): round-3 structure with fp32->bf16 convert.
// Atomic epilogue onto out pre-initialized to feat by k_copy.
// ---------------------------------------------------------------------------
__global__ __launch_bounds__(256, 3) void k_gemm2_f32(const float* __restrict__ A32,
                                                      const bhalf* __restrict__ ht,
                                                      const float* __restrict__ rsr,
                                                      const int* __restrict__ flag,
                                                      float* __restrict__ out) {
    __shared__ __align__(16) bhalf lsA[128 * 32];
    __shared__ __align__(16) bhalf lsB[128 * 32];
    const int n0   = blockIdx.x * 128;
    const int m0   = blockIdx.y * 128;
    const int K0   = blockIdx.z * (NN / 4);
    const int t    = threadIdx.x;
    const int lane = t & 63, wave = t >> 6;
    const int wm = (wave >> 1) * 64, wn = (wave & 1) * 64;
    const int quad = lane >> 4, rsel = lane & 15;
    f32x4 acc[4][4];
#pragma unroll
    for (int a = 0; a < 4; ++a)
#pragma unroll
        for (int bq = 0; bq < 4; ++bq)
#pragma unroll
            for (int e = 0; e < 4; ++e) acc[a][bq][e] = 0.f;

    for (int k0 = K0; k0 < K0 + NN / 4; k0 += 32) {
#pragma unroll
        for (int i = 0; i < 4; ++i) {
            const int ch = i * 256 + t;
            const int r = ch >> 3, s8 = ch & 7;
            const float4 v = *(const float4*)(A32 + (size_t)(m0 + r) * NN + k0 + s8 * 4);
            bhalf4 o;
            o[0] = (bhalf)v.x; o[1] = (bhalf)v.y; o[2] = (bhalf)v.z; o[3] = (bhalf)v.w;
            *(bhalf4*)(lsA + sw_off(r, s8 >> 1) + (s8 & 1) * 4) = o;
        }
#pragma unroll
        for (int i = 0; i < 2; ++i) {
            const int ch = i * 256 + t;
            const int r = ch >> 2, seg = ch & 3;
            const bhalf8 v = *(const bhalf8*)(ht + (size_t)(n0 + r) * NN + k0 + seg * 8);
            *(bhalf8*)(lsB + sw_off(r, seg)) = v;
        }
        __syncthreads();
        bhalf8 af[4], bf[4];
#pragma unroll
        for (int i = 0; i < 4; ++i) {
            af[i] = *(const bhalf8*)(lsA + sw_off(wm + i * 16 + rsel, quad));
            bf[i] = *(const bhalf8*)(lsB + sw_off(wn + i * 16 + rsel, quad));
        }
#pragma unroll
        for (int mt = 0; mt < 4; ++mt)
#pragma unroll
            for (int nt = 0; nt < 4; ++nt)
                acc[mt][nt] = __builtin_amdgcn_mfma_f32_16x16x32_bf16(af[mt], bf[nt],
                                                                      acc[mt][nt], 0, 0, 0);
        __syncthreads();
    }
    const int fl = *flag;
    if (fl) return;
#pragma unroll
    for (int mt = 0; mt < 4; ++mt) {
        const int ibase = m0 + wm + mt * 16 + quad * 4;
#pragma unroll
        for (int rg = 0; rg < 4; ++rg) {
            const int i   = ibase + rg;
            const float s = rsr[i];
#pragma unroll
            for (int nt = 0; nt < 4; ++nt) {
                const int j = n0 + wn + nt * 16 + rsel;
                atomicAdd(&out[(size_t)i * CC + j], s * acc[mt][nt][rg]);
            }
        }
    }
}

// ---------------------------------------------------------------------------
// Workspace layout:
//   0         row_deg  f32[8192]
//   32768     col_deg  f32[8192]
//   65536     rsqrt_row f32[8192]
//   98304     rsqrt_col f32[8192]
//   131072    flag int
//   262144    ht bf16[512*8192]          (8 MB)
//   16777216  A_bf16 bf16[8192*8192]     (128 MB)
//   150994944 partials bf16[4][8192*512] (32 MB)
// ---------------------------------------------------------------------------
extern "C" void kernel_launch(void* const* d_in, const int* in_sizes, int n_in,
                              void* d_out, int out_size, void* d_ws, size_t ws_size,
                              hipStream_t stream) {
    const float* feat = (const float*)d_in[0];
    const float* adj  = (const float*)d_in[1];
    const float* W    = (const float*)d_in[2];
    const float* bias = (const float*)d_in[3];
    float* out = (float*)d_out;

    char* ws       = (char*)d_ws;
    float* row_deg = (float*)(ws);
    float* col_deg = (float*)(ws + 32768);
    float* rsr     = (float*)(ws + 65536);
    float* rsc     = (float*)(ws + 98304);
    int* flag      = (int*)(ws + 131072);
    bhalf* ht      = (bhalf*)(ws + 262144);
    bhalf* Abf     = (bhalf*)(ws + 16777216);
    bhalf* part    = (bhalf*)(ws + 150994944);

    const bool use_bf16 =
        ws_size >= (size_t)150994944 + (size_t)4 * NN * CC * sizeof(bhalf);

    hipMemsetAsync(d_ws, 0, 131072 + 64, stream);

    if (use_bf16) {
        k_degrees<1><<<dim3(8, 256), 256, 0, stream>>>(adj, row_deg, col_deg, Abf);
        k_finalize<<<32, 256, 0, stream>>>(row_deg, col_deg, rsr, rsc, flag);
        k_h<<<dim3(4, 64), 256, 0, stream>>>(feat, W, bias, rsc, ht);
        k_gemm2_bf<<<dim3(2, 64, 4), 512, 0, stream>>>(Abf, ht, part);
        k_reduce<<<NN * CC / 4 / 256, 256, 0, stream>>>((const float4*)feat,
                                                        part, rsr, flag,
                                                        (float4*)out);
    } else {
        k_copy<<<NN * CC / 4 / 256, 256, 0, stream>>>((const float4*)feat, (float4*)out);
        k_degrees<0><<<dim3(8, 256), 256, 0, stream>>>(adj, row_deg, col_deg, nullptr);
        k_finalize<<<32, 256, 0, stream>>>(row_deg, col_deg, rsr, rsc, flag);
        k_h<<<dim3(4, 64), 256, 0, stream>>>(feat, W, bias, rsc, ht);
        k_gemm2_f32<<<dim3(4, 64, 4), 256, 0, stream>>>(adj, ht, rsr, flag, out);
    }
}